// Round 1
// baseline (417.868 us; speedup 1.0000x reference)
//
#include <hip/hip_runtime.h>
#include <math.h>

#define EPS_BN 1e-5f

__device__ __forceinline__ float warp_sum(float v) {
    for (int off = 32; off > 0; off >>= 1) v += __shfl_down(v, off);
    return v;
}

// ---------------------------------------------------------------------------
// Kernel A: effective stage-1 weights.
// W_eff[g][c][k] = sum_f w_spat[g,f,c] * w_time[f,0,k]   (25,64,10)
// bias_eff[g]    = sum_f (sum_c w_spat[g,f,c]) * b_time[f]
// ---------------------------------------------------------------------------
__global__ __launch_bounds__(256) void k_weff(
    const float* __restrict__ w_time, const float* __restrict__ b_time,
    const float* __restrict__ w_spat,
    float* __restrict__ weff, float* __restrict__ beff) {
    int idx = blockIdx.x * 256 + threadIdx.x;
    if (idx < 16000) {
        int g = idx / 640, r = idx % 640;
        int c = r / 10, k = r % 10;
        float s = 0.f;
#pragma unroll
        for (int f = 0; f < 25; ++f)
            s = fmaf(w_spat[g * 1600 + f * 64 + c], w_time[f * 10 + k], s);
        weff[idx] = s;
    } else if (idx < 16025) {
        int g = idx - 16000;
        float s = 0.f;
        for (int f = 0; f < 25; ++f) {
            float acc = 0.f;
            for (int c = 0; c < 64; ++c) acc += w_spat[g * 1600 + f * 64 + c];
            s = fmaf(acc, b_time[f], s);
        }
        beff[g] = s;
    }
}

// ---------------------------------------------------------------------------
// Kernel 1: fused conv_time+conv_spat (as conv with W_eff) + BN + ELU + pool3.
// x: (128, 64, 1000) -> z1: (128, 25, 330)
// grid (B, 11 time-tiles, 2 g-splits), block 256.
// LDS: weights 13*640*4=33.3KB + x tile 64*105*4=26.9KB = 60.2KB
// ---------------------------------------------------------------------------
__global__ __launch_bounds__(256) void k_conv1(
    const float* __restrict__ x, const float* __restrict__ weff,
    const float* __restrict__ beff,
    const float* __restrict__ bng, const float* __restrict__ bnb,
    const float* __restrict__ bnm, const float* __restrict__ bnv,
    float* __restrict__ z1) {
    __shared__ float ws[13 * 640];
    __shared__ float xs[64 * 105];
    const int b = blockIdx.x, tile = blockIdx.y, gs = blockIdx.z;
    const int g0 = gs * 13;
    const int ng = min(13, 25 - g0);
    const int t = threadIdx.x;

    for (int i = t; i < ng * 640; i += 256) ws[i] = weff[g0 * 640 + i];
    const int tx0 = tile * 96;
    for (int i = t; i < 64 * 105; i += 256) {
        int c = i / 105, j = i % 105;
        int tj = tx0 + j;
        xs[i] = (tj < 1000) ? x[b * 64000 + c * 1000 + tj] : 0.f;
    }
    __syncthreads();

    const int lane_to = t & 31, gl = t >> 5;
    const int to = tile * 32 + lane_to;
    const bool tvalid = (to < 330);

    for (int g = gl; g < ng; g += 8) {
        float s0 = 0.f, s1 = 0.f, s2 = 0.f;
        const float* wg = &ws[g * 640];
        const float* xr = &xs[3 * lane_to];
        for (int c = 0; c < 64; ++c) {
            float xv[12];
#pragma unroll
            for (int j = 0; j < 12; ++j) xv[j] = xr[c * 105 + j];
            const float* wr = &wg[c * 10];
#pragma unroll
            for (int k = 0; k < 10; ++k) {
                float w = wr[k];
                s0 = fmaf(xv[k], w, s0);
                s1 = fmaf(xv[k + 1], w, s1);
                s2 = fmaf(xv[k + 2], w, s2);
            }
        }
        if (tvalid) {
            int gg = g0 + g;
            float bias = beff[gg];
            float sc = bng[gg] / sqrtf(bnv[gg] + EPS_BN);
            float sh = bnb[gg] - bnm[gg] * sc;
            float y0 = (s0 + bias) * sc + sh;
            float y1 = (s1 + bias) * sc + sh;
            float y2 = (s2 + bias) * sc + sh;
            float e0 = y0 > 0.f ? y0 : expm1f(y0);
            float e1 = y1 > 0.f ? y1 : expm1f(y1);
            float e2 = y2 > 0.f ? y2 : expm1f(y2);
            z1[(b * 25 + gg) * 330 + to] = fmaxf(e0, fmaxf(e1, e2));
        }
    }
}

// ---------------------------------------------------------------------------
// Generic conv(K=10) + BN + ELU + pool3 for stages 2..4.
// Stages whole (CIN, TIN) input row for one b in LDS.
// ---------------------------------------------------------------------------
template <int CIN, int TIN, int TOUT, int COUT_T, int TO_TILE, bool W_IN_LDS>
__global__ __launch_bounds__(256) void k_conv(
    const float* __restrict__ zin, const float* __restrict__ wglob,
    const float* __restrict__ bng, const float* __restrict__ bnb,
    const float* __restrict__ bnm, const float* __restrict__ bnv,
    float* __restrict__ zout, int cout_total) {
    __shared__ float xs[CIN * TIN];
    __shared__ float ws[W_IN_LDS ? COUT_T * CIN * 10 : 1];
    const int b = blockIdx.x, gs = blockIdx.y;
    const int g0 = gs * COUT_T;
    const int ng = min(COUT_T, cout_total - g0);
    const int t = threadIdx.x;

    for (int i = t; i < CIN * TIN; i += 256) xs[i] = zin[b * CIN * TIN + i];
    if (W_IN_LDS) {
        for (int i = t; i < ng * CIN * 10; i += 256) ws[i] = wglob[g0 * CIN * 10 + i];
    }
    __syncthreads();

    constexpr int GLANES = 256 / TO_TILE;
    const int lane_to = t % TO_TILE, gl = t / TO_TILE;

    for (int g = gl; g < ng; g += GLANES) {
        const float* wrow = W_IN_LDS ? &ws[g * CIN * 10] : &wglob[(g0 + g) * CIN * 10];
        for (int to = lane_to; to < TOUT; to += TO_TILE) {
            float s0 = 0.f, s1 = 0.f, s2 = 0.f;
            for (int c = 0; c < CIN; ++c) {
                const float* xr = &xs[c * TIN + 3 * to];
                float xv[12];
#pragma unroll
                for (int j = 0; j < 12; ++j) xv[j] = xr[j];
                const float* wr = &wrow[c * 10];
#pragma unroll
                for (int k = 0; k < 10; ++k) {
                    float w = wr[k];
                    s0 = fmaf(xv[k], w, s0);
                    s1 = fmaf(xv[k + 1], w, s1);
                    s2 = fmaf(xv[k + 2], w, s2);
                }
            }
            int gg = g0 + g;
            float sc = bng[gg] / sqrtf(bnv[gg] + EPS_BN);
            float sh = bnb[gg] - bnm[gg] * sc;
            float y0 = s0 * sc + sh, y1 = s1 * sc + sh, y2 = s2 * sc + sh;
            float e0 = y0 > 0.f ? y0 : expm1f(y0);
            float e1 = y1 > 0.f ? y1 : expm1f(y1);
            float e2 = y2 > 0.f ? y2 : expm1f(y2);
            zout[(b * cout_total + gg) * TOUT + to] = fmaxf(e0, fmaxf(e1, e2));
        }
    }
}

// ---------------------------------------------------------------------------
// Kernel 5: classifier conv (time dim -> 1) + per-cluster expert head.
// z4: (128, 200, 7) -> feats (4,) -> h1 (512,) -> out (4,)
// One block per batch sample, 256 threads = 4 waves.
// ---------------------------------------------------------------------------
__global__ __launch_bounds__(256) void k_head(
    const float* __restrict__ z4, const float* __restrict__ w_cls,
    const float* __restrict__ b_cls, const int* __restrict__ cid,
    const float* __restrict__ hW1, const float* __restrict__ hb1,
    const float* __restrict__ hW2, const float* __restrict__ hb2,
    const float* __restrict__ hg, const float* __restrict__ hbe,
    const float* __restrict__ hm, const float* __restrict__ hv,
    float* __restrict__ out) {
    __shared__ float zs[1400];
    __shared__ float feats[4];
    __shared__ float h1s[512];
    const int b = blockIdx.x, t = threadIdx.x;
    for (int i = t; i < 1400; i += 256) zs[i] = z4[b * 1400 + i];
    __syncthreads();

    const int wv = t >> 6, lane = t & 63;
    {
        float p = 0.f;
        for (int i = lane; i < 1400; i += 64) p = fmaf(zs[i], w_cls[wv * 1400 + i], p);
        p = warp_sum(p);
        if (lane == 0) feats[wv] = p + b_cls[wv];
    }
    __syncthreads();

    const int c = cid[b];
    const float f0 = feats[0], f1 = feats[1], f2 = feats[2], f3 = feats[3];
    for (int h = t; h < 512; h += 256) {
        const float* w1 = &hW1[(c * 512 + h) * 4];
        float v = f0 * w1[0] + f1 * w1[1] + f2 * w1[2] + f3 * w1[3] + hb1[c * 512 + h];
        float sc = hg[c * 512 + h] / sqrtf(hv[c * 512 + h] + EPS_BN);
        v = (v - hm[c * 512 + h]) * sc + hbe[c * 512 + h];
        h1s[h] = fmaxf(v, 0.f);
    }
    __syncthreads();
    {
        float p = 0.f;
        for (int i = lane; i < 512; i += 64) p = fmaf(h1s[i], hW2[(c * 4 + wv) * 512 + i], p);
        p = warp_sum(p);
        if (lane == 0) out[b * 4 + wv] = p + hb2[c * 4 + wv];
    }
}

// ---------------------------------------------------------------------------
extern "C" void kernel_launch(void* const* d_in, const int* in_sizes, int n_in,
                              void* d_out, int out_size, void* d_ws, size_t ws_size,
                              hipStream_t stream) {
    const float* x      = (const float*)d_in[0];
    const int*   cid    = (const int*)d_in[1];
    const float* w_time = (const float*)d_in[2];
    const float* b_time = (const float*)d_in[3];
    const float* w_spat = (const float*)d_in[4];
    const float* w2     = (const float*)d_in[5];
    const float* w3     = (const float*)d_in[6];
    const float* w4     = (const float*)d_in[7];
    const float* w_cls  = (const float*)d_in[8];
    const float* b_cls  = (const float*)d_in[9];
    const float* hW1    = (const float*)d_in[10];
    const float* hb1    = (const float*)d_in[11];
    const float* hW2    = (const float*)d_in[12];
    const float* hb2    = (const float*)d_in[13];
    const float* hg     = (const float*)d_in[14];
    const float* hbe    = (const float*)d_in[15];
    const float* hm     = (const float*)d_in[16];
    const float* hv     = (const float*)d_in[17];
    const float* g1  = (const float*)d_in[18];
    const float* be1 = (const float*)d_in[19];
    const float* m1  = (const float*)d_in[20];
    const float* v1  = (const float*)d_in[21];
    const float* g2  = (const float*)d_in[22];
    const float* be2 = (const float*)d_in[23];
    const float* m2  = (const float*)d_in[24];
    const float* v2  = (const float*)d_in[25];
    const float* g3  = (const float*)d_in[26];
    const float* be3 = (const float*)d_in[27];
    const float* m3  = (const float*)d_in[28];
    const float* v3  = (const float*)d_in[29];
    const float* g4  = (const float*)d_in[30];
    const float* be4 = (const float*)d_in[31];
    const float* m4  = (const float*)d_in[32];
    const float* v4  = (const float*)d_in[33];

    float* ws_f = (float*)d_ws;
    float* weff = ws_f;                 // 16000
    float* beff = weff + 16000;         // 25 (pad to 32)
    float* z1   = beff + 32;            // 128*25*330  = 1,056,000
    float* z2   = z1 + 1056000;         // 128*50*107  =   684,800
    float* z3   = z2 + 684800;          // 128*100*32  =   409,600
    float* z4   = z3 + 409600;          // 128*200*7   =   179,200

    float* out = (float*)d_out;

    k_weff<<<63, 256, 0, stream>>>(w_time, b_time, w_spat, weff, beff);

    k_conv1<<<dim3(128, 11, 2), 256, 0, stream>>>(x, weff, beff, g1, be1, m1, v1, z1);

    // conv2: (128,25,330) -> (128,50,107)
    k_conv<25, 330, 107, 25, 32, true><<<dim3(128, 2), 256, 0, stream>>>(
        z1, w2, g2, be2, m2, v2, z2, 50);

    // conv3: (128,50,107) -> (128,100,32)
    k_conv<50, 107, 32, 20, 32, true><<<dim3(128, 5), 256, 0, stream>>>(
        z2, w3, g3, be3, m3, v3, z3, 100);

    // conv4: (128,100,32) -> (128,200,7)  (weights 800KB: read from L2)
    k_conv<100, 32, 7, 100, 8, false><<<dim3(128, 2), 256, 0, stream>>>(
        z3, w4, g4, be4, m4, v4, z4, 200);

    k_head<<<128, 256, 0, stream>>>(z4, w_cls, b_cls, cid, hW1, hb1, hW2, hb2,
                                    hg, hbe, hm, hv, out);
}

// Round 2
// 362.787 us; speedup vs baseline: 1.1518x; 1.1518x over previous
//
#include <hip/hip_runtime.h>
#include <math.h>

#define EPS_BN 1e-5f

__device__ __forceinline__ float warp_sum(float v) {
    for (int off = 32; off > 0; off >>= 1) v += __shfl_down(v, off);
    return v;
}

__device__ __forceinline__ float elu1(float y) { return y > 0.f ? y : expm1f(y); }

// ws float offsets
#define OFF_WEFF   0          // [25][64][16]   25600
#define OFF_W2P    25600      // [50][25][16]   20000
#define OFF_W3P    45600      // [100][50][16]  80000
#define OFF_W4P    125600     // [200][100][16] 320000
#define OFF_SC1    445600
#define OFF_SH1    445625
#define OFF_SC2    445650
#define OFF_SH2    445700
#define OFF_SC3    445750
#define OFF_SH3    445850
#define OFF_SC4    445950
#define OFF_SH4    446150
#define OFF_Z1     446368     // 128*25*330 = 1,056,000
#define OFF_Z2     1502368    // 128*50*107 =   684,800
#define OFF_Z3     2187168    // 128*100*32 =   409,600
#define OFF_PBUF   OFF_Z1     // [3][128][21][200] = 1,612,800  (aliases z1+z2, dead by conv4)

// ---------------------------------------------------------------------------
// Prep 1: weff_p[g][c][16] (k<10 real, rest 0) + folded BN1 (bias absorbed).
// ---------------------------------------------------------------------------
__global__ __launch_bounds__(256) void k_weff(
    const float* __restrict__ w_time, const float* __restrict__ b_time,
    const float* __restrict__ w_spat,
    const float* __restrict__ g1, const float* __restrict__ be1,
    const float* __restrict__ m1, const float* __restrict__ v1,
    float* __restrict__ ws_f) {
    int idx = blockIdx.x * 256 + threadIdx.x;
    if (idx < 25600) {
        int g = idx >> 10, rem = idx & 1023, c = rem >> 4, k = rem & 15;
        float s = 0.f;
        if (k < 10) {
#pragma unroll
            for (int f = 0; f < 25; ++f)
                s = fmaf(w_spat[g * 1600 + f * 64 + c], w_time[f * 10 + k], s);
        }
        ws_f[OFF_WEFF + idx] = s;
    } else if (idx < 25625) {
        int g = idx - 25600;
        float beff = 0.f;
        for (int f = 0; f < 25; ++f) {
            float acc = 0.f;
            for (int c = 0; c < 64; ++c) acc += w_spat[g * 1600 + f * 64 + c];
            beff = fmaf(acc, b_time[f], beff);
        }
        float sc = g1[g] * rsqrtf(v1[g] + EPS_BN);
        ws_f[OFF_SC1 + g] = sc;
        ws_f[OFF_SH1 + g] = be1[g] - m1[g] * sc + beff * sc;
    }
}

// ---------------------------------------------------------------------------
// Prep 2: pad-pack w2/w3/w4 to 16-float rows + folded BN 2..4.
// ---------------------------------------------------------------------------
__global__ __launch_bounds__(256) void k_pack(
    const float* __restrict__ w2, const float* __restrict__ w3,
    const float* __restrict__ w4,
    const float* __restrict__ g2, const float* __restrict__ be2,
    const float* __restrict__ m2, const float* __restrict__ v2,
    const float* __restrict__ g3, const float* __restrict__ be3,
    const float* __restrict__ m3, const float* __restrict__ v3,
    const float* __restrict__ g4, const float* __restrict__ be4,
    const float* __restrict__ m4, const float* __restrict__ v4,
    float* __restrict__ ws_f) {
    int idx = blockIdx.x * 256 + threadIdx.x;
    if (idx < 20000) {
        int g = idx / 400, r = idx % 400, c = r >> 4, k = r & 15;
        ws_f[OFF_W2P + idx] = (k < 10) ? w2[(g * 25 + c) * 10 + k] : 0.f;
    } else if (idx < 100000) {
        int j = idx - 20000;
        int g = j / 800, r = j % 800, c = r >> 4, k = r & 15;
        ws_f[OFF_W3P + j] = (k < 10) ? w3[(g * 50 + c) * 10 + k] : 0.f;
    } else if (idx < 420000) {
        int j = idx - 100000;
        int g = j / 1600, r = j % 1600, c = r >> 4, k = r & 15;
        ws_f[OFF_W4P + j] = (k < 10) ? w4[(g * 100 + c) * 10 + k] : 0.f;
    } else if (idx < 420050) {
        int i = idx - 420000;
        float sc = g2[i] * rsqrtf(v2[i] + EPS_BN);
        ws_f[OFF_SC2 + i] = sc;
        ws_f[OFF_SH2 + i] = be2[i] - m2[i] * sc;
    } else if (idx < 420150) {
        int i = idx - 420050;
        float sc = g3[i] * rsqrtf(v3[i] + EPS_BN);
        ws_f[OFF_SC3 + i] = sc;
        ws_f[OFF_SH3 + i] = be3[i] - m3[i] * sc;
    } else if (idx < 420350) {
        int i = idx - 420150;
        float sc = g4[i] * rsqrtf(v4[i] + EPS_BN);
        ws_f[OFF_SC4 + i] = sc;
        ws_f[OFF_SH4 + i] = be4[i] - m4[i] * sc;
    }
}

// ---------------------------------------------------------------------------
// conv1: x (128,64,1000) -> z1 (128,25,330). grid (128, 6 time-tiles).
// Wave-uniform g (s_load weights), lane = pooled output within 64-tile.
// ---------------------------------------------------------------------------
__global__ __launch_bounds__(256) void k1(
    const float* __restrict__ x, const float* __restrict__ ws_f,
    float* __restrict__ z1) {
    __shared__ float xs[64 * 201];
    const float* wp  = ws_f + OFF_WEFF;
    const float* sc1 = ws_f + OFF_SC1;
    const float* sh1 = ws_f + OFF_SH1;
    const int b = blockIdx.x, tile = blockIdx.y;
    const int t = threadIdx.x;
    const int x0 = tile * 192;
    for (int i = t; i < 64 * 201; i += 256) {
        int c = i / 201, j = i - c * 201;
        int xj = x0 + j;
        xs[i] = (xj < 1000) ? x[b * 64000 + c * 1000 + xj] : 0.f;
    }
    __syncthreads();

    const int lane = t & 63;
    const int wv = __builtin_amdgcn_readfirstlane(t >> 6);
    const int to = tile * 64 + lane;

    float acc[7][3];
#pragma unroll
    for (int j = 0; j < 7; ++j) acc[j][0] = acc[j][1] = acc[j][2] = 0.f;

    for (int c = 0; c < 64; ++c) {
        const float* xr = &xs[c * 201 + 3 * lane];
        float xv[12];
#pragma unroll
        for (int j = 0; j < 12; ++j) xv[j] = xr[j];
#pragma unroll
        for (int jg = 0; jg < 7; ++jg) {
            int g = wv + 4 * jg;
            if (g < 25) {
                const float* wr = wp + (g * 64 + c) * 16;
#pragma unroll
                for (int k = 0; k < 10; ++k) {
                    float w = wr[k];
                    acc[jg][0] = fmaf(xv[k],     w, acc[jg][0]);
                    acc[jg][1] = fmaf(xv[k + 1], w, acc[jg][1]);
                    acc[jg][2] = fmaf(xv[k + 2], w, acc[jg][2]);
                }
            }
        }
    }
    if (to < 330) {
#pragma unroll
        for (int jg = 0; jg < 7; ++jg) {
            int g = wv + 4 * jg;
            if (g < 25) {
                float sc = sc1[g], sh = sh1[g];
                float e0 = elu1(fmaf(acc[jg][0], sc, sh));
                float e1 = elu1(fmaf(acc[jg][1], sc, sh));
                float e2 = elu1(fmaf(acc[jg][2], sc, sh));
                z1[(b * 25 + g) * 330 + to] = fmaxf(e0, fmaxf(e1, e2));
            }
        }
    }
}

// ---------------------------------------------------------------------------
// conv2: z1 (128,25,330) -> z2 (128,50,107). grid (128, 4 g-blocks).
// T=2 contiguous outputs per lane.
// ---------------------------------------------------------------------------
__global__ __launch_bounds__(256) void k2(
    const float* __restrict__ ws_f, float* __restrict__ z2) {
    __shared__ float xs[8320];  // 25*330 = 8250 used (+pad for idle-lane reads)
    const float* z1  = ws_f + OFF_Z1;
    const float* wp  = ws_f + OFF_W2P;
    const float* scp = ws_f + OFF_SC2;
    const float* shp = ws_f + OFF_SH2;
    const int b = blockIdx.x, gb = blockIdx.y;
    const int g0 = (gb * 50) / 4, g1 = ((gb + 1) * 50) / 4;
    const int t = threadIdx.x;
    for (int i = t; i < 8250; i += 256) xs[i] = z1[b * 8250 + i];
    __syncthreads();

    const int lane = t & 63;
    const int wv = __builtin_amdgcn_readfirstlane(t >> 6);

    float acc[4][2][3];
#pragma unroll
    for (int j = 0; j < 4; ++j)
#pragma unroll
        for (int a = 0; a < 2; ++a) acc[j][a][0] = acc[j][a][1] = acc[j][a][2] = 0.f;

    for (int c = 0; c < 25; ++c) {
        const float* xr = &xs[c * 330 + 6 * lane];
        float xv[15];
#pragma unroll
        for (int j = 0; j < 15; ++j) xv[j] = xr[j];
#pragma unroll
        for (int jg = 0; jg < 4; ++jg) {
            int g = g0 + wv + 4 * jg;
            if (g < g1) {
                const float* wr = wp + (g * 25 + c) * 16;
#pragma unroll
                for (int k = 0; k < 10; ++k) {
                    float w = wr[k];
#pragma unroll
                    for (int ti = 0; ti < 2; ++ti) {
                        acc[jg][ti][0] = fmaf(xv[3 * ti + k],     w, acc[jg][ti][0]);
                        acc[jg][ti][1] = fmaf(xv[3 * ti + k + 1], w, acc[jg][ti][1]);
                        acc[jg][ti][2] = fmaf(xv[3 * ti + k + 2], w, acc[jg][ti][2]);
                    }
                }
            }
        }
    }
#pragma unroll
    for (int jg = 0; jg < 4; ++jg) {
        int g = g0 + wv + 4 * jg;
        if (g < g1) {
            float sc = scp[g], sh = shp[g];
#pragma unroll
            for (int ti = 0; ti < 2; ++ti) {
                int to = 2 * lane + ti;
                if (to < 107) {
                    float e0 = elu1(fmaf(acc[jg][ti][0], sc, sh));
                    float e1 = elu1(fmaf(acc[jg][ti][1], sc, sh));
                    float e2 = elu1(fmaf(acc[jg][ti][2], sc, sh));
                    z2[(b * 50 + g) * 107 + to] = fmaxf(e0, fmaxf(e1, e2));
                }
            }
        }
    }
}

// ---------------------------------------------------------------------------
// conv3: z2 (128,50,107) -> z3 (128,100,32). grid (64 b-pairs, 8 g-blocks).
// lane = (bh, to): bh = lane>>5 picks sample of pair, to = lane&31.
// ---------------------------------------------------------------------------
__global__ __launch_bounds__(256) void k3(
    const float* __restrict__ ws_f, float* __restrict__ z3) {
    __shared__ float xs[2 * 5350];
    const float* z2  = ws_f + OFF_Z2;
    const float* wp  = ws_f + OFF_W3P;
    const float* scp = ws_f + OFF_SC3;
    const float* shp = ws_f + OFF_SH3;
    const int b0 = blockIdx.x * 2, gb = blockIdx.y;
    const int g0 = (gb * 100) / 8, g1 = ((gb + 1) * 100) / 8;
    const int t = threadIdx.x;
    for (int i = t; i < 10700; i += 256) xs[i] = z2[b0 * 5350 + i];
    __syncthreads();

    const int lane = t & 63;
    const int bh = lane >> 5, to = lane & 31;
    const int wv = __builtin_amdgcn_readfirstlane(t >> 6);

    float acc[4][3];
#pragma unroll
    for (int j = 0; j < 4; ++j) acc[j][0] = acc[j][1] = acc[j][2] = 0.f;

    for (int c = 0; c < 50; ++c) {
        const float* xr = &xs[bh * 5350 + c * 107 + 3 * to];
        float xv[12];
#pragma unroll
        for (int j = 0; j < 12; ++j) xv[j] = xr[j];
#pragma unroll
        for (int jg = 0; jg < 4; ++jg) {
            int g = g0 + wv + 4 * jg;
            if (g < g1) {
                const float* wr = wp + (g * 50 + c) * 16;
#pragma unroll
                for (int k = 0; k < 10; ++k) {
                    float w = wr[k];
                    acc[jg][0] = fmaf(xv[k],     w, acc[jg][0]);
                    acc[jg][1] = fmaf(xv[k + 1], w, acc[jg][1]);
                    acc[jg][2] = fmaf(xv[k + 2], w, acc[jg][2]);
                }
            }
        }
    }
#pragma unroll
    for (int jg = 0; jg < 4; ++jg) {
        int g = g0 + wv + 4 * jg;
        if (g < g1) {
            float sc = scp[g], sh = shp[g];
            float e0 = elu1(fmaf(acc[jg][0], sc, sh));
            float e1 = elu1(fmaf(acc[jg][1], sc, sh));
            float e2 = elu1(fmaf(acc[jg][2], sc, sh));
            z3[((b0 + bh) * 100 + g) * 32 + to] = fmaxf(e0, fmaxf(e1, e2));
        }
    }
}

// ---------------------------------------------------------------------------
// conv4 partials: z3 (128,100,32) -> pbuf[cq][b][to*3+w][g]. grid (128, 3).
// g per lane; weights via per-lane float4 (L2); x via uniform-address loads.
// ---------------------------------------------------------------------------
__global__ __launch_bounds__(256) void k4(
    const float* __restrict__ ws_f, float* __restrict__ pbuf) {
    const float* z3 = ws_f + OFF_Z3;
    const float* wp = ws_f + OFF_W4P;
    const int b = blockIdx.x, cq = blockIdx.y;
    const int cs = (cq * 100) / 3, ce = ((cq + 1) * 100) / 3;
    const int g = threadIdx.x;
    if (g >= 200) return;

    float acc[7][3];
#pragma unroll
    for (int j = 0; j < 7; ++j) acc[j][0] = acc[j][1] = acc[j][2] = 0.f;

    for (int c = cs; c < ce; ++c) {
        const float* xr = z3 + (b * 100 + c) * 32;
        float xv[32];
#pragma unroll
        for (int q = 0; q < 8; ++q) {
            float4 f = *(const float4*)(xr + 4 * q);
            xv[4 * q] = f.x; xv[4 * q + 1] = f.y; xv[4 * q + 2] = f.z; xv[4 * q + 3] = f.w;
        }
        const float* wr = wp + (g * 100 + c) * 16;
        float4 wa = *(const float4*)(wr);
        float4 wb = *(const float4*)(wr + 4);
        float2 wc = *(const float2*)(wr + 8);
        float w[10] = {wa.x, wa.y, wa.z, wa.w, wb.x, wb.y, wb.z, wb.w, wc.x, wc.y};
#pragma unroll
        for (int k = 0; k < 10; ++k) {
#pragma unroll
            for (int to = 0; to < 7; ++to) {
                acc[to][0] = fmaf(xv[3 * to + k],     w[k], acc[to][0]);
                acc[to][1] = fmaf(xv[3 * to + k + 1], w[k], acc[to][1]);
                acc[to][2] = fmaf(xv[3 * to + k + 2], w[k], acc[to][2]);
            }
        }
    }
#pragma unroll
    for (int to = 0; to < 7; ++to)
#pragma unroll
        for (int wn = 0; wn < 3; ++wn)
            pbuf[((cq * 128 + b) * 21 + (to * 3 + wn)) * 200 + g] = acc[to][wn];
}

// ---------------------------------------------------------------------------
// head: combine conv4 partials + BN4/ELU/pool + classifier conv + expert MLP.
// ---------------------------------------------------------------------------
__global__ __launch_bounds__(256) void k5(
    const float* __restrict__ ws_f,
    const float* __restrict__ w_cls, const float* __restrict__ b_cls,
    const int* __restrict__ cid,
    const float* __restrict__ hW1, const float* __restrict__ hb1,
    const float* __restrict__ hW2, const float* __restrict__ hb2,
    const float* __restrict__ hg, const float* __restrict__ hbe,
    const float* __restrict__ hm, const float* __restrict__ hv,
    float* __restrict__ out) {
    __shared__ float zs[1400];
    __shared__ float feats[4];
    __shared__ float h1s[512];
    const float* pbuf = ws_f + OFF_PBUF;
    const float* sc4  = ws_f + OFF_SC4;
    const float* sh4  = ws_f + OFF_SH4;
    const int b = blockIdx.x, t = threadIdx.x;

    for (int i = t; i < 1400; i += 256) {
        int g = i / 7, r = i - g * 7;
        float sc = sc4[g], sh = sh4[g];
        float best = -1e30f;
#pragma unroll
        for (int wn = 0; wn < 3; ++wn) {
            float s = 0.f;
#pragma unroll
            for (int cq = 0; cq < 3; ++cq)
                s += pbuf[((cq * 128 + b) * 21 + (r * 3 + wn)) * 200 + g];
            best = fmaxf(best, elu1(fmaf(s, sc, sh)));
        }
        zs[i] = best;
    }
    __syncthreads();

    const int wv = t >> 6, lane = t & 63;
    {
        float p = 0.f;
        for (int i = lane; i < 1400; i += 64) p = fmaf(zs[i], w_cls[wv * 1400 + i], p);
        p = warp_sum(p);
        if (lane == 0) feats[wv] = p + b_cls[wv];
    }
    __syncthreads();

    const int c = cid[b];
    const float f0 = feats[0], f1 = feats[1], f2 = feats[2], f3 = feats[3];
    for (int h = t; h < 512; h += 256) {
        const float* w1 = &hW1[(c * 512 + h) * 4];
        float v = f0 * w1[0] + f1 * w1[1] + f2 * w1[2] + f3 * w1[3] + hb1[c * 512 + h];
        float sc = hg[c * 512 + h] * rsqrtf(hv[c * 512 + h] + EPS_BN);
        v = (v - hm[c * 512 + h]) * sc + hbe[c * 512 + h];
        h1s[h] = fmaxf(v, 0.f);
    }
    __syncthreads();
    {
        float p = 0.f;
        for (int i = lane; i < 512; i += 64) p = fmaf(h1s[i], hW2[(c * 4 + wv) * 512 + i], p);
        p = warp_sum(p);
        if (lane == 0) out[b * 4 + wv] = p + hb2[c * 4 + wv];
    }
}

// ---------------------------------------------------------------------------
extern "C" void kernel_launch(void* const* d_in, const int* in_sizes, int n_in,
                              void* d_out, int out_size, void* d_ws, size_t ws_size,
                              hipStream_t stream) {
    const float* x      = (const float*)d_in[0];
    const int*   cid    = (const int*)d_in[1];
    const float* w_time = (const float*)d_in[2];
    const float* b_time = (const float*)d_in[3];
    const float* w_spat = (const float*)d_in[4];
    const float* w2     = (const float*)d_in[5];
    const float* w3     = (const float*)d_in[6];
    const float* w4     = (const float*)d_in[7];
    const float* w_cls  = (const float*)d_in[8];
    const float* b_cls  = (const float*)d_in[9];
    const float* hW1    = (const float*)d_in[10];
    const float* hb1    = (const float*)d_in[11];
    const float* hW2    = (const float*)d_in[12];
    const float* hb2    = (const float*)d_in[13];
    const float* hg     = (const float*)d_in[14];
    const float* hbe    = (const float*)d_in[15];
    const float* hm     = (const float*)d_in[16];
    const float* hv     = (const float*)d_in[17];
    const float* g1  = (const float*)d_in[18];
    const float* be1 = (const float*)d_in[19];
    const float* m1  = (const float*)d_in[20];
    const float* v1  = (const float*)d_in[21];
    const float* g2  = (const float*)d_in[22];
    const float* be2 = (const float*)d_in[23];
    const float* m2  = (const float*)d_in[24];
    const float* v2  = (const float*)d_in[25];
    const float* g3  = (const float*)d_in[26];
    const float* be3 = (const float*)d_in[27];
    const float* m3  = (const float*)d_in[28];
    const float* v3  = (const float*)d_in[29];
    const float* g4  = (const float*)d_in[30];
    const float* be4 = (const float*)d_in[31];
    const float* m4  = (const float*)d_in[32];
    const float* v4  = (const float*)d_in[33];

    float* ws_f = (float*)d_ws;
    float* out  = (float*)d_out;

    k_weff<<<102, 256, 0, stream>>>(w_time, b_time, w_spat, g1, be1, m1, v1, ws_f);
    k_pack<<<1642, 256, 0, stream>>>(w2, w3, w4, g2, be2, m2, v2, g3, be3, m3, v3,
                                     g4, be4, m4, v4, ws_f);

    k1<<<dim3(128, 6), 256, 0, stream>>>(x, ws_f, ws_f + OFF_Z1);
    k2<<<dim3(128, 4), 256, 0, stream>>>(ws_f, ws_f + OFF_Z2);
    k3<<<dim3(64, 8), 256, 0, stream>>>(ws_f, ws_f + OFF_Z3);
    k4<<<dim3(128, 3), 256, 0, stream>>>(ws_f, ws_f + OFF_PBUF);
    k5<<<128, 256, 0, stream>>>(ws_f, w_cls, b_cls, cid, hW1, hb1, hW2, hb2,
                                hg, hbe, hm, hv, out);
}

// Round 3
// 112.802 us; speedup vs baseline: 3.7044x; 3.2161x over previous
//
#include <hip/hip_runtime.h>
#include <math.h>

#define EPS_BN 1e-5f

typedef __attribute__((ext_vector_type(8))) short short8;
typedef __attribute__((ext_vector_type(4))) float f32x4;

__device__ __forceinline__ unsigned short f2bf(float f) {
    unsigned int u = __float_as_uint(f);
    u = (u + 0x7fffu + ((u >> 16) & 1u)) >> 16;
    return (unsigned short)u;
}
__device__ __forceinline__ float bf2f(unsigned short s) {
    return __uint_as_float(((unsigned int)s) << 16);
}
__device__ __forceinline__ float elu1(float y) { return y > 0.f ? y : expm1f(y); }
__device__ __forceinline__ float warp_sum(float v) {
    for (int off = 32; off > 0; off >>= 1) v += __shfl_down(v, off);
    return v;
}

// ---------------- workspace layout ----------------
// ushort region (bf16 weights), base = d_ws
#define UW1 0        // [10][32][64]   20480
#define UW2 20480    // [10][64][32]   20480
#define UW3 40960    // [10][128][64]  81920
#define UW4 122880   // [10][224][128] 286720  -> end 409600 ush = 819200 B
// float bias region at byte 819200: [32][64][128][224] = 448 floats -> ends 820992
#define BB1 0
#define BB2 32
#define BB3 96
#define BB4 224
// bf16 activation region at byte 820992 (ushort indices):
#define UZ1 0        // [128][330][32]  = 1,351,680
#define UZ2 1351680  // [128][107][64]  =   876,544
#define UZ3 2228224  // [128][32][128]  =   524,288
#define UZ4 2752512  // [128][7][200]   =   179,200

// ---------------------------------------------------------------------------
// prep: build BN-folded, zero-padded bf16 weights + fused biases.
// ---------------------------------------------------------------------------
__global__ __launch_bounds__(256) void kprep(
    const float* __restrict__ w_time, const float* __restrict__ b_time,
    const float* __restrict__ w_spat,
    const float* __restrict__ w2, const float* __restrict__ w3,
    const float* __restrict__ w4,
    const float* __restrict__ g1, const float* __restrict__ be1,
    const float* __restrict__ m1, const float* __restrict__ v1,
    const float* __restrict__ g2, const float* __restrict__ be2,
    const float* __restrict__ m2, const float* __restrict__ v2,
    const float* __restrict__ g3, const float* __restrict__ be3,
    const float* __restrict__ m3, const float* __restrict__ v3,
    const float* __restrict__ g4, const float* __restrict__ be4,
    const float* __restrict__ m4, const float* __restrict__ v4,
    unsigned short* __restrict__ wsu, float* __restrict__ biasf) {
    int idx = blockIdx.x * 256 + threadIdx.x;
    if (idx < 20480) {                       // Wpk1 [10][32][64]
        int k = idx >> 11, g = (idx >> 6) & 31, c = idx & 63;
        float val = 0.f;
        if (g < 25) {
            float s = 0.f;
#pragma unroll
            for (int f = 0; f < 25; ++f)
                s = fmaf(w_spat[g * 1600 + f * 64 + c], w_time[f * 10 + k], s);
            val = s * (g1[g] * rsqrtf(v1[g] + EPS_BN));
        }
        wsu[UW1 + idx] = f2bf(val);
    } else if (idx < 40960) {                // Wpk2 [10][64][32]
        int j = idx - 20480;
        int k = j >> 11, g = (j >> 5) & 63, c = j & 31;
        float val = 0.f;
        if (g < 50 && c < 25)
            val = w2[(g * 25 + c) * 10 + k] * (g2[g] * rsqrtf(v2[g] + EPS_BN));
        wsu[UW2 + j] = f2bf(val);
    } else if (idx < 122880) {               // Wpk3 [10][128][64]
        int j = idx - 40960;
        int k = j >> 13, g = (j >> 6) & 127, c = j & 63;
        float val = 0.f;
        if (g < 100 && c < 50)
            val = w3[(g * 50 + c) * 10 + k] * (g3[g] * rsqrtf(v3[g] + EPS_BN));
        wsu[UW3 + j] = f2bf(val);
    } else if (idx < 409600) {               // Wpk4 [10][224][128]
        int j = idx - 122880;
        int k = j / 28672, r = j % 28672, g = r >> 7, c = r & 127;
        float val = 0.f;
        if (g < 200 && c < 100)
            val = w4[(g * 100 + c) * 10 + k] * (g4[g] * rsqrtf(v4[g] + EPS_BN));
        wsu[UW4 + j] = f2bf(val);
    } else if (idx < 410048) {               // biases
        int j = idx - 409600;
        if (j < 32) {
            int g = j; float val = 0.f;
            if (g < 25) {
                float beff = 0.f;
                for (int f = 0; f < 25; ++f) {
                    float a = 0.f;
                    for (int c = 0; c < 64; ++c) a += w_spat[g * 1600 + f * 64 + c];
                    beff = fmaf(a, b_time[f], beff);
                }
                float sc = g1[g] * rsqrtf(v1[g] + EPS_BN);
                val = be1[g] - m1[g] * sc + beff * sc;
            }
            biasf[BB1 + g] = val;
        } else if (j < 96) {
            int g = j - 32; float val = 0.f;
            if (g < 50) { float sc = g2[g] * rsqrtf(v2[g] + EPS_BN); val = be2[g] - m2[g] * sc; }
            biasf[BB2 + g] = val;
        } else if (j < 224) {
            int g = j - 96; float val = 0.f;
            if (g < 100) { float sc = g3[g] * rsqrtf(v3[g] + EPS_BN); val = be3[g] - m3[g] * sc; }
            biasf[BB3 + g] = val;
        } else {
            int g = j - 224; float val = 0.f;
            if (g < 200) { float sc = g4[g] * rsqrtf(v4[g] + EPS_BN); val = be4[g] - m4[g] * sc; }
            biasf[BB4 + g] = val;
        }
    }
}

// ---------------------------------------------------------------------------
// unified MFMA conv(K=10) + bias + ELU + maxpool3 stage.
// A = xT tile (LDS, [row=t][c] bf16, RS ≡ 8 mod 16 -> conflict-free b128),
// B = Wpk[k][g][c] (global/L2), D[t][g] per 16x16x32 bf16 MFMA.
// Wave job: (g-block of 32, t-chunk of 96 pre-pool = 32 pooled).
// ---------------------------------------------------------------------------
template<int CPAD, int RS, int SP, int TT, int TPC, int NCHUNK, int JMAX,
         int NTCH, int NGB, int GPAD, int TIN, int TPOOL, int GSTORE, int NGV,
         int ROWS_AL, int WPB, int T0B, bool ST1>
__global__ __launch_bounds__(64 * WPB) void kconv(
    const float* __restrict__ x, const unsigned short* __restrict__ zin,
    const unsigned short* __restrict__ wpk, const float* __restrict__ bias,
    unsigned short* __restrict__ zout) {
    __shared__ __align__(16) unsigned short xT[ROWS_AL * RS];
    __shared__ __align__(16) unsigned short zb[WPB * TPC * 16 * 32];

    const int b = blockIdx.x, by = blockIdx.y;
    const int t = threadIdx.x;
    const int t0b = by * T0B;

    // ---- staging: build xT (bf16, transposed layout [t][c]) ----
    if constexpr (ST1) {
        const float* xb = x + b * 64000;
        for (int idx = t; idx < 32 * (ROWS_AL / 4); idx += 64 * WPB) {
            int cp = idx / (ROWS_AL / 4), t4 = idx % (ROWS_AL / 4);
            int r0 = t4 * 4, tg = t0b + r0;
            float4 va = {0, 0, 0, 0}, vb = {0, 0, 0, 0};
            if (tg < 1000) {
                va = *(const float4*)(xb + (2 * cp) * 1000 + tg);
                vb = *(const float4*)(xb + (2 * cp + 1) * 1000 + tg);
            }
            const float* pa = (const float*)&va;
            const float* pb = (const float*)&vb;
#pragma unroll
            for (int i2 = 0; i2 < 4; ++i2) {
                unsigned int pk = (unsigned int)f2bf(pa[i2]) |
                                  ((unsigned int)f2bf(pb[i2]) << 16);
                *(unsigned int*)&xT[(r0 + i2) * RS + 2 * cp] = pk;
            }
        }
    } else {
        const unsigned short* zi = zin + b * TIN * CPAD;
        for (int idx = t; idx < ROWS_AL * (CPAD / 2); idx += 64 * WPB) {
            int r = idx / (CPAD / 2), cp = idx % (CPAD / 2);
            unsigned int v = (r < TIN) ? *(const unsigned int*)&zi[r * CPAD + 2 * cp] : 0u;
            *(unsigned int*)&xT[r * RS + 2 * cp] = v;
        }
    }
    __syncthreads();

    const int lane = t & 63;
    const int wv = __builtin_amdgcn_readfirstlane(t >> 6);
    const int jobid = by * WPB + wv;
    const int gbi = jobid / NTCH, tci = jobid % NTCH;
    const bool active = (gbi < NGB);
    const int lm = lane & 15, h8 = lane >> 4;
    const int tl0 = tci * 96 - t0b;   // local row base of this wave's span
    const int po0 = tci * 32;         // absolute pooled base

    f32x4 acc[TT][2];
#pragma unroll
    for (int i = 0; i < TT; ++i) {
        acc[i][0] = (f32x4){0.f, 0.f, 0.f, 0.f};
        acc[i][1] = (f32x4){0.f, 0.f, 0.f, 0.f};
    }

    if (active) {
        const int abase = (tl0 + lm) * RS + h8 * 8;
        const unsigned short* wp = wpk + (gbi * 32 + lm) * CPAD + h8 * 8;
#pragma unroll
        for (int k = 0; k < 10; ++k) {
            short8 w0[SP], w1[SP];
#pragma unroll
            for (int s = 0; s < SP; ++s) {
                w0[s] = *(const short8*)(wp + k * (GPAD * CPAD) + s * 32);
                w1[s] = *(const short8*)(wp + k * (GPAD * CPAD) + 16 * CPAD + s * 32);
            }
#pragma unroll
            for (int s = 0; s < SP; ++s) {
#pragma unroll
                for (int tt = 0; tt < TT; ++tt) {
                    short8 a = *(const short8*)&xT[abase + (tt * 16 + k) * RS + s * 32];
                    acc[tt][0] = __builtin_amdgcn_mfma_f32_16x16x32_bf16(
                        a, w0[s], acc[tt][0], 0, 0, 0);
                    acc[tt][1] = __builtin_amdgcn_mfma_f32_16x16x32_bf16(
                        a, w1[s], acc[tt][1], 0, 0, 0);
                }
            }
        }

        // ---- epilogue: bias + ELU -> zb (bf16) -> pool3 -> global ----
        float bv0 = bias[gbi * 32 + lm];
        float bv1 = bias[gbi * 32 + 16 + lm];
        unsigned short* zbw = &zb[wv * (TPC * 16 * 32)];
        const int gloc = lane & 31, hh = lane >> 5;
#pragma unroll
        for (int ch = 0; ch < NCHUNK; ++ch) {
#pragma unroll
            for (int ti = 0; ti < TPC; ++ti) {
                int ttg = ch * TPC + ti;
#pragma unroll
                for (int r = 0; r < 4; ++r) {
                    float v0 = elu1(acc[ttg][0][r] + bv0);
                    float v1 = elu1(acc[ttg][1][r] + bv1);
                    int row = ti * 16 + 4 * h8 + r;
                    zbw[row * 32 + lm] = f2bf(v0);
                    zbw[row * 32 + 16 + lm] = f2bf(v1);
                }
            }
#pragma unroll
            for (int j = 0; j < JMAX; ++j) {
                int po = hh + 2 * j;
                if (3 * po + 2 < TPC * 16) {
                    float q0 = bf2f(zbw[(3 * po) * 32 + gloc]);
                    float q1 = bf2f(zbw[(3 * po + 1) * 32 + gloc]);
                    float q2 = bf2f(zbw[(3 * po + 2) * 32 + gloc]);
                    float mx = fmaxf(q0, fmaxf(q1, q2));
                    int poa = po0 + ch * 16 + po;
                    int ga = gbi * 32 + gloc;
                    if (poa < TPOOL && ga < GSTORE)
                        zout[b * TPOOL * GSTORE + poa * GSTORE + ga] =
                            (ga < NGV) ? f2bf(mx) : (unsigned short)0;
                }
            }
        }
    }
}

// ---------------------------------------------------------------------------
// head: classifier conv (t->1) + per-cluster expert MLP. z4 bf16 [b][7][200].
// ---------------------------------------------------------------------------
__global__ __launch_bounds__(256) void k5(
    const unsigned short* __restrict__ z4, const float* __restrict__ w_cls,
    const float* __restrict__ b_cls, const int* __restrict__ cid,
    const float* __restrict__ hW1, const float* __restrict__ hb1,
    const float* __restrict__ hW2, const float* __restrict__ hb2,
    const float* __restrict__ hg, const float* __restrict__ hbe,
    const float* __restrict__ hm, const float* __restrict__ hv,
    float* __restrict__ out) {
    __shared__ float zs[1400];
    __shared__ float feats[4];
    __shared__ float h1s[512];
    const int b = blockIdx.x, t = threadIdx.x;
    for (int i = t; i < 1400; i += 256) zs[i] = bf2f(z4[b * 1400 + i]);
    __syncthreads();

    const int wv = t >> 6, lane = t & 63;
    {
        float p = 0.f;
        for (int i = lane; i < 1400; i += 64) {
            int po = i / 200, g = i - po * 200;
            p = fmaf(zs[i], w_cls[wv * 1400 + g * 7 + po], p);
        }
        p = warp_sum(p);
        if (lane == 0) feats[wv] = p + b_cls[wv];
    }
    __syncthreads();

    const int c = cid[b];
    const float f0 = feats[0], f1 = feats[1], f2 = feats[2], f3 = feats[3];
    for (int h = t; h < 512; h += 256) {
        const float* w1 = &hW1[(c * 512 + h) * 4];
        float v = f0 * w1[0] + f1 * w1[1] + f2 * w1[2] + f3 * w1[3] + hb1[c * 512 + h];
        float sc = hg[c * 512 + h] * rsqrtf(hv[c * 512 + h] + EPS_BN);
        v = (v - hm[c * 512 + h]) * sc + hbe[c * 512 + h];
        h1s[h] = fmaxf(v, 0.f);
    }
    __syncthreads();
    {
        float p = 0.f;
        for (int i = lane; i < 512; i += 64) p = fmaf(h1s[i], hW2[(c * 4 + wv) * 512 + i], p);
        p = warp_sum(p);
        if (lane == 0) out[b * 4 + wv] = p + hb2[c * 4 + wv];
    }
}

// ---------------------------------------------------------------------------
extern "C" void kernel_launch(void* const* d_in, const int* in_sizes, int n_in,
                              void* d_out, int out_size, void* d_ws, size_t ws_size,
                              hipStream_t stream) {
    const float* x      = (const float*)d_in[0];
    const int*   cid    = (const int*)d_in[1];
    const float* w_time = (const float*)d_in[2];
    const float* b_time = (const float*)d_in[3];
    const float* w_spat = (const float*)d_in[4];
    const float* w2     = (const float*)d_in[5];
    const float* w3     = (const float*)d_in[6];
    const float* w4     = (const float*)d_in[7];
    const float* w_cls  = (const float*)d_in[8];
    const float* b_cls  = (const float*)d_in[9];
    const float* hW1    = (const float*)d_in[10];
    const float* hb1    = (const float*)d_in[11];
    const float* hW2    = (const float*)d_in[12];
    const float* hb2    = (const float*)d_in[13];
    const float* hg     = (const float*)d_in[14];
    const float* hbe    = (const float*)d_in[15];
    const float* hm     = (const float*)d_in[16];
    const float* hv     = (const float*)d_in[17];
    const float* g1  = (const float*)d_in[18];
    const float* be1 = (const float*)d_in[19];
    const float* m1  = (const float*)d_in[20];
    const float* v1  = (const float*)d_in[21];
    const float* g2  = (const float*)d_in[22];
    const float* be2 = (const float*)d_in[23];
    const float* m2  = (const float*)d_in[24];
    const float* v2  = (const float*)d_in[25];
    const float* g3  = (const float*)d_in[26];
    const float* be3 = (const float*)d_in[27];
    const float* m3  = (const float*)d_in[28];
    const float* v3  = (const float*)d_in[29];
    const float* g4  = (const float*)d_in[30];
    const float* be4 = (const float*)d_in[31];
    const float* m4  = (const float*)d_in[32];
    const float* v4  = (const float*)d_in[33];

    unsigned short* wsu = (unsigned short*)d_ws;
    float* biasf = (float*)((char*)d_ws + 819200);
    unsigned short* zb = (unsigned short*)((char*)d_ws + 820992);
    float* out = (float*)d_out;

    kprep<<<1602, 256, 0, stream>>>(w_time, b_time, w_spat, w2, w3, w4,
                                    g1, be1, m1, v1, g2, be2, m2, v2,
                                    g3, be3, m3, v3, g4, be4, m4, v4,
                                    wsu, biasf);

    // stage1: x(128,64,1000) -> z1 bf16 [128][330][32]
    kconv<64, 72, 2, 6, 3, 2, 8, 11, 1, 32, 1000, 330, 32, 25, 204, 2, 192, true>
        <<<dim3(128, 6), 128, 0, stream>>>(x, nullptr, wsu + UW1, biasf + BB1, zb + UZ1);
    // stage2: z1 -> z2 bf16 [128][107][64]
    kconv<32, 40, 1, 6, 3, 2, 8, 4, 2, 64, 330, 107, 64, 50, 396, 4, 0, false>
        <<<dim3(128, 2), 256, 0, stream>>>(nullptr, zb + UZ1, wsu + UW2, biasf + BB2, zb + UZ2);
    // stage3: z2 -> z3 bf16 [128][32][128]
    kconv<64, 72, 2, 6, 3, 2, 8, 1, 4, 128, 107, 32, 128, 100, 108, 2, 0, false>
        <<<dim3(128, 2), 128, 0, stream>>>(nullptr, zb + UZ2, wsu + UW3, biasf + BB3, zb + UZ3);
    // stage4: z3 -> z4 bf16 [128][7][200]
    kconv<128, 136, 4, 2, 2, 1, 5, 1, 7, 224, 32, 7, 200, 200, 44, 2, 0, false>
        <<<dim3(128, 4), 128, 0, stream>>>(nullptr, zb + UZ3, wsu + UW4, biasf + BB4, zb + UZ4);

    k5<<<128, 256, 0, stream>>>(zb + UZ4, w_cls, b_cls, cid, hW1, hb1, hW2, hb2,
                                hg, hbe, hm, hv, out);
}